// Round 1
// baseline (149.036 us; speedup 1.0000x reference)
//
#include <hip/hip_runtime.h>
#include <math.h>

#define N      4096
#define NIMG   2048
#define TXO    56            // net output cols per wave-strip (64 lanes - 8 halo)
#define HR     40            // output rows per wave-strip
#define DRS    48            // D rows per strip = HR + 8
#define IPP    27            // img patch pitch (cols), odd -> bank-spread
#define IPR    34            // img patch rows (max; u-span 64 -> r0-span 32 -> 34)
#define VB     64            // hblur row-buffer pitch
#define NSX    74            // ceil(4096/56)
#define NSY    103           // ceil(4096/40)
#define NSTRIP (NSX * NSY)   // 7622 wave-strips
#define NBLK   ((NSTRIP + 3) / 4)

// Gaussian kernel sigma=1, r=4 (double-precision eval of reference formula)
#define KW0 0.00013383063f
#define KW1 0.00443186160f
#define KW2 0.05399112800f
#define KW3 0.24197144000f
#define KW4 0.39894346870f

__device__ __forceinline__ int symi(int g) {
    g = (g < 0) ? (-1 - g) : g;
    g = (g >= N) ? (2 * N - 1 - g) : g;
    return g;
}

// Barrier-free design: each wave owns one 56x40 output strip.
//  - vertical blur: 16-deep register sliding window (no LDS transpose of D)
//  - LDS strictly wave-private (img patch + 8-row hblur buffer); same-wave DS
//    ops complete in order -> no __syncthreads anywhere.
//  - the (harness-verified) generic symmetric/bilinear mapping is used for ALL
//    lanes, so interior and edge strips share one code path.
__global__ __launch_bounds__(256, 5)
void TensorAugment_79216376807666_kernel(const float* __restrict__ img,
                                         const float* __restrict__ noise,
                                         float* __restrict__ out) {
    __shared__ float SH[4 * (IPR * IPP + 8 * VB)];   // 4 waves x 5720 B = 22880 B

    const int tid  = threadIdx.x;
    const int lane = tid & 63;
    const int wave = tid >> 6;

    float* const IP   = SH + wave * (IPR * IPP + 8 * VB);
    float* const VBUF = IP + IPR * IPP;

    const int strip0 = blockIdx.x * 4 + wave;
    if (strip0 >= NSTRIP) return;                    // whole-wave exit; no barriers exist

    const int strip = __builtin_amdgcn_readfirstlane(strip0);
    const int sx = strip % NSX;
    const int sy = strip / NSX;
    const int x0 = sx * TXO;                         // lanes cover gx = x0-4 .. x0+59
    const int y0 = sy * HR;

    // ---- wave-uniform staged img ranges (x -> img rows, y -> img cols) ----
    int gxa = x0 - 4, gxb = x0 + 59;
    int mxa = symi(gxa), mxb = symi(gxb);
    int gxmin = min(mxa, mxb), gxmax = max(mxa, mxb);
    if (gxa <= 0) gxmin = 0;
    if (gxb >= N - 1) gxmax = N - 1;
    int umin = (N - 1) - gxmax, umax = (N - 1) - gxmin;
    int r0min = (umin - 1) >> 1;
    int r0max = (umax - 1) >> 1;
    int nrows = r0max - r0min + 2;                   // <= 34

    int gya = y0 - 4, gyb = y0 + DRS - 5;            // D rows gy = y0-4 .. y0+43
    int mya = symi(gya), myb = symi(gyb);
    int gymin = min(mya, myb), gymax = max(mya, myb);
    if (gya <= 0) gymin = 0;
    if (gyb >= N - 1) gymax = N - 1;
    int c0min = (gymin - 1) >> 1;
    int c0max = (gymax - 1) >> 1;
    int ncols = c0max - c0min + 2;                   // <= 26

    // ---- stage img patch (unrolled so the 17 loads stay in flight) ----
    {
        const int c  = lane & 31;
        const int rb = lane >> 5;
        const bool cok = (c < ncols);
#pragma unroll
        for (int k = 0; k < 17; ++k) {
            const int r = rb + 2 * k;
            if (cok && r < nrows) {
                const int ir = min(max(r0min + r, 0), NIMG - 1);
                const int ic = min(max(c0min + c, 0), NIMG - 1);
                IP[r * IPP + c] = img[ir * NIMG + ic];
            }
        }
    }

    // ---- per-lane x mapping (generic symmetric path, valid for all lanes) ----
    const int gx  = x0 - 4 + lane;
    const int gxm = symi(gx);
    const int u   = (N - 1) - gxm;
    const int r0  = (u - 1) >> 1;
    const float wr1 = (u & 1) ? 0.25f : 0.75f;
    const float wr0 = 1.0f - wr1;
    const int a0  = (r0 - r0min) * IPP;
    const bool oklane = (lane >= 4) && (lane < 60) && (gx < N);
    const int rbase = min(max(lane - 4, 0), VB - 9); // clamped hblur window base

    const float kk[9] = {KW0, KW1, KW2, KW3, KW4, KW3, KW2, KW1, KW0};

    auto nzld = [&](int dr) -> float {
        const int gym = symi(y0 - 4 + dr);
        return noise[(size_t)gym * N + gxm];
    };
    auto drow = [&](int dr, float nz) -> float {
        const int gym = symi(y0 - 4 + dr);
        const int jc  = ((gym - 1) >> 1) - c0min;
        const float wc1 = (gym & 1) ? 0.25f : 0.75f;
        const float wc0 = 1.0f - wc1;
        const float f0 = IP[a0 + jc],       f1 = IP[a0 + jc + 1];
        const float f2 = IP[a0 + IPP + jc], f3 = IP[a0 + IPP + jc + 1];
        const float top = fmaf(wc0, f0, wc1 * f1);
        const float bot = fmaf(wc0, f2, wc1 * f3);
        return fmaf(0.01f, nz, fmaf(wr0, top, wr1 * bot));
    };

    // ---- prologue: D rows 0..15 into the register window ----
    float win[16];
    {
        float nz[16];
#pragma unroll
        for (int j = 0; j < 16; ++j) nz[j] = nzld(j);
#pragma unroll
        for (int j = 0; j < 16; ++j) win[j] = drow(j, nz[j]);
    }

    // ---- main loop: 5 chunks of 8 rows; noise for chunk ck prefetched under
    //      the blur compute of rows 8(ck-2)..8(ck-2)+7 ----
#pragma unroll 1
    for (int ck = 2; ck <= 6; ++ck) {
        float nz[8];
        if (ck < 6) {
#pragma unroll
            for (int j = 0; j < 8; ++j) nz[j] = nzld(8 * ck + j);
        }

        // vertical blur from registers -> wave-private VBUF (conflict-free)
#pragma unroll
        for (int j = 0; j < 8; ++j) {
            float acc = kk[0] * win[j];
#pragma unroll
            for (int i = 1; i < 9; ++i) acc = fmaf(kk[i], win[j + i], acc);
            VBUF[j * VB + lane] = acc;
        }

        // horizontal blur + relu + log1p + coalesced store (in-order DS: the
        // reads below see this wave's writes above without any barrier)
        const int gyb0 = y0 + 8 * (ck - 2);
#pragma unroll
        for (int j = 0; j < 8; ++j) {
            const int vb = j * VB + rbase;
            float acc = kk[0] * VBUF[vb];
#pragma unroll
            for (int i = 1; i < 9; ++i) acc = fmaf(kk[i], VBUF[vb + i], acc);
            acc = fmaxf(acc, 0.0f);
            const float r = __logf(1.0f + acc);
            const int gy = gyb0 + j;
            if (oklane && gy < N) out[(size_t)gy * N + gx] = r;
        }

        // slide the register window and append the prefetched chunk
        if (ck < 6) {
#pragma unroll
            for (int i = 0; i < 8; ++i) win[i] = win[i + 8];
#pragma unroll
            for (int j = 0; j < 8; ++j) win[8 + j] = drow(8 * ck + j, nz[j]);
        }
    }
}

extern "C" void kernel_launch(void* const* d_in, const int* in_sizes, int n_in,
                              void* d_out, int out_size, void* d_ws, size_t ws_size,
                              hipStream_t stream) {
    const float* img   = (const float*)d_in[0];   // (1, 2048, 2048) f32
    const float* noise = (const float*)d_in[1];   // (1, 4096, 4096) f32
    float* out = (float*)d_out;                   // (1, 4096, 4096) f32

    dim3 grid(NBLK);                              // 1906 blocks x 256 (4 wave-strips each)
    TensorAugment_79216376807666_kernel<<<grid, 256, 0, stream>>>(img, noise, out);
}

// Round 2
// 145.892 us; speedup vs baseline: 1.0215x; 1.0215x over previous
//
#include <hip/hip_runtime.h>
#include <math.h>

#define N      4096
#define NIMG   2048
#define TXO    56            // net output cols per wave-strip (64 lanes - 8 halo)
#define HR     40            // output rows per wave-strip
#define DRS    48            // D rows per strip = HR + 8
#define IPP    27            // img patch pitch (cols), odd -> bank-spread
#define IPR    34            // img patch rows (max)
#define NSX    74            // ceil(4096/56)
#define NSY    103           // ceil(4096/40)
#define NSTRIP (NSX * NSY)   // 7622 wave-strips
#define NBLK   ((NSTRIP + 3) / 4)

// Gaussian kernel sigma=1, r=4 (double-precision eval of reference formula)
#define KW0 0.00013383063f
#define KW1 0.00443186160f
#define KW2 0.05399112800f
#define KW3 0.24197144000f
#define KW4 0.39894346870f

__device__ __forceinline__ int symi(int g) {
    g = (g < 0) ? (-1 - g) : g;
    g = (g >= N) ? (2 * N - 1 - g) : g;
    return g;
}

// Wave-autonomous 56x40 strips, zero barriers, LDS = img patch only.
// Bilinear factorization: D(x,y) = wc0(y)*g(x,jc) + wc1(y)*g(x,jc+1) + noise,
// where g(x,j) = wr0*IP[r0][j] + wr1*IP[r0+1][j] is reused across all D rows.
// For y-interior strips jc/wc are compile-time affine -> 3 FMA per D row.
// Horizontal blur via ds_bpermute (no LDS buffer, no write->read stall).

// produce D rows [8*M .. 8*M+7] into win[OFS..OFS+7] (all array idx static)
#define PRODUCE8(M, OFS, NZA, NOFS)                                            \
    do {                                                                       \
        if (yin) {                                                             \
            const int ab_ = a0 + 4 * (M);                                      \
            float g0 = fmaf(wr0, IP[ab_ + 0], wr1 * IP[ab_ + IPP + 0]);        \
            float g1 = fmaf(wr0, IP[ab_ + 1], wr1 * IP[ab_ + IPP + 1]);        \
            float g2 = fmaf(wr0, IP[ab_ + 2], wr1 * IP[ab_ + IPP + 2]);        \
            float g3 = fmaf(wr0, IP[ab_ + 3], wr1 * IP[ab_ + IPP + 3]);        \
            float g4 = fmaf(wr0, IP[ab_ + 4], wr1 * IP[ab_ + IPP + 4]);        \
            float g5 = fmaf(wr0, IP[ab_ + 5], wr1 * IP[ab_ + IPP + 5]);        \
            win[(OFS) + 0] = fmaf(0.25f, g0, fmaf(0.75f, g1, 0.01f * (NZA)[(NOFS) + 0])); \
            win[(OFS) + 1] = fmaf(0.75f, g1, fmaf(0.25f, g2, 0.01f * (NZA)[(NOFS) + 1])); \
            win[(OFS) + 2] = fmaf(0.25f, g1, fmaf(0.75f, g2, 0.01f * (NZA)[(NOFS) + 2])); \
            win[(OFS) + 3] = fmaf(0.75f, g2, fmaf(0.25f, g3, 0.01f * (NZA)[(NOFS) + 3])); \
            win[(OFS) + 4] = fmaf(0.25f, g2, fmaf(0.75f, g3, 0.01f * (NZA)[(NOFS) + 4])); \
            win[(OFS) + 5] = fmaf(0.75f, g3, fmaf(0.25f, g4, 0.01f * (NZA)[(NOFS) + 5])); \
            win[(OFS) + 6] = fmaf(0.25f, g3, fmaf(0.75f, g4, 0.01f * (NZA)[(NOFS) + 6])); \
            win[(OFS) + 7] = fmaf(0.75f, g4, fmaf(0.25f, g5, 0.01f * (NZA)[(NOFS) + 7])); \
        } else {                                                               \
            _Pragma("unroll")                                                  \
            for (int j_ = 0; j_ < 8; ++j_) {                                   \
                const int dr_  = 8 * (M) + j_;                                 \
                const int gym_ = symi(y0 - 4 + dr_);                           \
                const int jc_  = ((gym_ - 1) >> 1) - c0min;                    \
                const float wc1_ = (gym_ & 1) ? 0.25f : 0.75f;                 \
                const float wc0_ = 1.0f - wc1_;                                \
                const float f0_ = IP[a0 + jc_],       f1_ = IP[a0 + jc_ + 1];  \
                const float f2_ = IP[a0 + IPP + jc_], f3_ = IP[a0 + IPP + jc_ + 1]; \
                const float top_ = fmaf(wc0_, f0_, wc1_ * f1_);                \
                const float bot_ = fmaf(wc0_, f2_, wc1_ * f3_);                \
                win[(OFS) + j_] = fmaf(0.01f, (NZA)[(NOFS) + j_],              \
                                       fmaf(wr0, top_, wr1 * bot_));           \
            }                                                                  \
        }                                                                      \
    } while (0)

__global__ __launch_bounds__(256, 6)
void TensorAugment_79216376807666_kernel(const float* __restrict__ img,
                                         const float* __restrict__ noise,
                                         float* __restrict__ out) {
    __shared__ float SH[4 * IPR * IPP];              // 4 waves x 3672 B = 14688 B

    const int tid  = threadIdx.x;
    const int lane = tid & 63;
    const int wave = tid >> 6;

    float* const IP = SH + wave * (IPR * IPP);

    const int strip0 = blockIdx.x * 4 + wave;
    if (strip0 >= NSTRIP) return;                    // whole-wave exit; no barriers exist

    const int strip = __builtin_amdgcn_readfirstlane(strip0);
    const int sx = strip % NSX;
    const int sy = strip / NSX;
    const int x0 = sx * TXO;                         // lanes cover gx = x0-4 .. x0+59
    const int y0 = sy * HR;
    const bool yin = (sy > 0) && (sy < NSY - 1);     // y-interior: static jc/wc pattern

    // ---- wave-uniform staged img ranges (x -> img rows, y -> img cols) ----
    int gxa = x0 - 4, gxb = x0 + 59;
    int mxa = symi(gxa), mxb = symi(gxb);
    int gxmin = min(mxa, mxb), gxmax = max(mxa, mxb);
    if (gxa <= 0) gxmin = 0;
    if (gxb >= N - 1) gxmax = N - 1;
    int umin = (N - 1) - gxmax, umax = (N - 1) - gxmin;
    int r0min = (umin - 1) >> 1;
    int r0max = (umax - 1) >> 1;
    int nrows = r0max - r0min + 2;                   // <= 34

    int gya = y0 - 4, gyb = y0 + DRS - 5;            // D rows gy = y0-4 .. y0+43
    int mya = symi(gya), myb = symi(gyb);
    int gymin = min(mya, myb), gymax = max(mya, myb);
    if (gya <= 0) gymin = 0;
    if (gyb >= N - 1) gymax = N - 1;
    int c0min = (gymin - 1) >> 1;
    int c0max = (gymax - 1) >> 1;
    int ncols = c0max - c0min + 2;                   // <= 26

    // ---- stage img patch (wave-private; same-wave DS ops are in-order) ----
    {
        const int c  = lane & 31;
        const int rb = lane >> 5;
        const bool cok = (c < ncols);
#pragma unroll
        for (int k = 0; k < 17; ++k) {
            const int r = rb + 2 * k;
            if (cok && r < nrows) {
                const int ir = min(max(r0min + r, 0), NIMG - 1);
                const int ic = min(max(c0min + c, 0), NIMG - 1);
                IP[r * IPP + c] = img[ir * NIMG + ic];
            }
        }
    }

    // ---- per-lane x mapping (generic symmetric path, valid for all lanes) ----
    const int gx  = x0 - 4 + lane;
    const int gxm = symi(gx);
    const int u   = (N - 1) - gxm;
    const int r0  = (u - 1) >> 1;
    const float wr1 = (u & 1) ? 0.25f : 0.75f;
    const float wr0 = 1.0f - wr1;
    const int a0  = (r0 - r0min) * IPP;
    const bool oklane = (lane >= 4) && (lane < 60) && (gx < N);

    // ---- bpermute addresses for the 9-tap horizontal blur (bytes) ----
    int ba[9];
#pragma unroll
    for (int d = 0; d < 9; ++d) ba[d] = 4 * (lane + d - 4);

    // per-lane noise column base (row y0-4), valid deref only for yin
    const float* const nzb = noise + ((size_t)max(y0 - 4, 0) * N + gxm);

    // ---- prologue: D rows 0..15 ----
    float win[16];
    {
        float nzp[16];
        if (yin) {
#pragma unroll
            for (int j = 0; j < 16; ++j) nzp[j] = nzb[(size_t)j * N];
        } else {
#pragma unroll
            for (int j = 0; j < 16; ++j)
                nzp[j] = noise[(size_t)symi(y0 - 4 + j) * N + gxm];
        }
        PRODUCE8(0, 0, nzp, 0);
        PRODUCE8(1, 8, nzp, 8);
    }

    // ---- main loop: 5 chunks of 8 output rows ----
#pragma unroll 1
    for (int ck = 2; ck <= 6; ++ck) {
        // prefetch next chunk's noise under this chunk's compute
        float nz8[8];
        if (ck < 6) {
            if (yin) {
                const float* nr = nzb + (size_t)(8 * ck) * N;
#pragma unroll
                for (int j = 0; j < 8; ++j) nz8[j] = nr[(size_t)j * N];
            } else {
#pragma unroll
                for (int j = 0; j < 8; ++j)
                    nz8[j] = noise[(size_t)symi(y0 - 4 + 8 * ck + j) * N + gxm];
            }
        }

        const int gyb0 = y0 + 8 * (ck - 2);
#pragma unroll
        for (int j = 0; j < 8; ++j) {
            // vertical blur from the register window
            float v = KW0 * win[j];
            v = fmaf(KW1, win[j + 1], v);
            v = fmaf(KW2, win[j + 2], v);
            v = fmaf(KW3, win[j + 3], v);
            v = fmaf(KW4, win[j + 4], v);
            v = fmaf(KW3, win[j + 5], v);
            v = fmaf(KW2, win[j + 6], v);
            v = fmaf(KW1, win[j + 7], v);
            v = fmaf(KW0, win[j + 8], v);
            // horizontal blur across lanes via bpermute (halo lanes discard)
            const int vi = __float_as_int(v);
            float acc = KW4 * v;
            acc = fmaf(KW0, __int_as_float(__builtin_amdgcn_ds_bpermute(ba[0], vi)), acc);
            acc = fmaf(KW1, __int_as_float(__builtin_amdgcn_ds_bpermute(ba[1], vi)), acc);
            acc = fmaf(KW2, __int_as_float(__builtin_amdgcn_ds_bpermute(ba[2], vi)), acc);
            acc = fmaf(KW3, __int_as_float(__builtin_amdgcn_ds_bpermute(ba[3], vi)), acc);
            acc = fmaf(KW3, __int_as_float(__builtin_amdgcn_ds_bpermute(ba[5], vi)), acc);
            acc = fmaf(KW2, __int_as_float(__builtin_amdgcn_ds_bpermute(ba[6], vi)), acc);
            acc = fmaf(KW1, __int_as_float(__builtin_amdgcn_ds_bpermute(ba[7], vi)), acc);
            acc = fmaf(KW0, __int_as_float(__builtin_amdgcn_ds_bpermute(ba[8], vi)), acc);
            acc = fmaxf(acc, 0.0f);
            const float r = __logf(1.0f + acc);
            const int gy = gyb0 + j;
            if (oklane && gy < N) out[(size_t)gy * N + gx] = r;
        }

        // slide the register window and append the prefetched chunk
        if (ck < 6) {
#pragma unroll
            for (int i = 0; i < 8; ++i) win[i] = win[i + 8];
            PRODUCE8(ck, 8, nz8, 0);
        }
    }
}

extern "C" void kernel_launch(void* const* d_in, const int* in_sizes, int n_in,
                              void* d_out, int out_size, void* d_ws, size_t ws_size,
                              hipStream_t stream) {
    const float* img   = (const float*)d_in[0];   // (1, 2048, 2048) f32
    const float* noise = (const float*)d_in[1];   // (1, 4096, 4096) f32
    float* out = (float*)d_out;                   // (1, 4096, 4096) f32

    dim3 grid(NBLK);                              // 1906 blocks x 256 (4 wave-strips each)
    TensorAugment_79216376807666_kernel<<<grid, 256, 0, stream>>>(img, noise, out);
}